// Round 1
// baseline (11514.742 us; speedup 1.0000x reference)
//
#include <hip/hip_runtime.h>
#include <hip/hip_cooperative_groups.h>
#include <cmath>

namespace cg = cooperative_groups;

// T=512, B=32, D=1024, H=1024, 3H=3072
// d_out: outputs (512*32*1024) ++ outputs[-1] (32*1024) ++ h_last (32*1024)  fp32

typedef short s8v  __attribute__((ext_vector_type(8)));   // 8 x bf16 (raw bits)
typedef float f4v  __attribute__((ext_vector_type(4)));   // MFMA accumulator

__device__ __forceinline__ short f2bf(float f) {
    return __builtin_bit_cast(short, (__bf16)f);          // RNE convert
}
__device__ __forceinline__ float bf2f(short s) {
    return (float)__builtin_bit_cast(__bf16, s);
}

// ---------------------------------------------------------------------------
// Transpose W [1024][3072] fp32  ->  Wt [3072][1024] bf16 (so B-fragments are
// contiguous-in-k 16B loads). LDS tile 32(k) x 64(n).
// ---------------------------------------------------------------------------
__global__ __launch_bounds__(256) void k_transpose_bf16(
        const float* __restrict__ W, short* __restrict__ Wt) {
    __shared__ short Ls[32][72];                 // pad 64->72 vs bank conflicts
    int bk = blockIdx.x & 31;                    // 32 k-tiles
    int bn = blockIdx.x >> 5;                    // 48 n-tiles
    int k0 = bk * 32, n0 = bn * 64;
    int tid = threadIdx.x;
    {
        int r  = tid >> 3;                       // 0..31 (k)
        int c0 = (tid & 7) * 8;                  // 0..56 (n)
        const float* src = W + (size_t)(k0 + r) * 3072 + n0 + c0;
        float4 f0 = *reinterpret_cast<const float4*>(src);
        float4 f1 = *reinterpret_cast<const float4*>(src + 4);
        Ls[r][c0+0] = f2bf(f0.x); Ls[r][c0+1] = f2bf(f0.y);
        Ls[r][c0+2] = f2bf(f0.z); Ls[r][c0+3] = f2bf(f0.w);
        Ls[r][c0+4] = f2bf(f1.x); Ls[r][c0+5] = f2bf(f1.y);
        Ls[r][c0+6] = f2bf(f1.z); Ls[r][c0+7] = f2bf(f1.w);
    }
    __syncthreads();
    {
        int j   = tid >> 2;                      // 0..63 (n)
        int kk0 = (tid & 3) * 8;                 // 0..24 (k)
        s8v v;
        #pragma unroll
        for (int s = 0; s < 8; ++s) v[s] = Ls[kk0 + s][j];
        *reinterpret_cast<s8v*>(Wt + (size_t)(n0 + j) * 1024 + k0 + kk0) = v;
    }
}

// ---------------------------------------------------------------------------
// gi = X @ W_ih  (bias folded in later).  M=16384, N=3072, K=1024.
// 64x64 tile / block, 4 waves in 2x2, each wave 32x32 via 4x mfma 16x16x32.
// Output stored bf16.
// ---------------------------------------------------------------------------
__global__ __launch_bounds__(256) void k_gemm_gi(
        const float* __restrict__ X, const short* __restrict__ Wt,
        short* __restrict__ gi) {
    __shared__ short As[64][40];                 // 32 k + pad 8 (2-way only)
    __shared__ short Bs[64][40];
    int bm = blockIdx.x & 255;                   // 256 m-tiles
    int bn = blockIdx.x >> 8;                    // 48 n-tiles
    int m0 = bm * 64, n0 = bn * 64;
    int tid = threadIdx.x;
    int wid = tid >> 6, l = tid & 63;
    int wm = wid >> 1, wn = wid & 1;
    int lr = l & 15, q = l >> 4;
    f4v acc[2][2] = {};
    int sr = tid >> 2;                           // 0..63
    int sc = (tid & 3) * 8;                      // 0,8,16,24

    for (int kc = 0; kc < 1024; kc += 32) {
        const float* asrc = X + (size_t)(m0 + sr) * 1024 + kc + sc;
        float4 f0 = *reinterpret_cast<const float4*>(asrc);
        float4 f1 = *reinterpret_cast<const float4*>(asrc + 4);
        s8v av;
        av[0]=f2bf(f0.x); av[1]=f2bf(f0.y); av[2]=f2bf(f0.z); av[3]=f2bf(f0.w);
        av[4]=f2bf(f1.x); av[5]=f2bf(f1.y); av[6]=f2bf(f1.z); av[7]=f2bf(f1.w);
        *reinterpret_cast<s8v*>(&As[sr][sc]) = av;
        *reinterpret_cast<s8v*>(&Bs[sr][sc]) =
            *reinterpret_cast<const s8v*>(Wt + (size_t)(n0 + sr) * 1024 + kc + sc);
        __syncthreads();
        // A[m=lr][k=q*8+j], B[k=q*8+j][n=lr]
        s8v a0 = *reinterpret_cast<const s8v*>(&As[wm*32 +  0 + lr][q*8]);
        s8v a1 = *reinterpret_cast<const s8v*>(&As[wm*32 + 16 + lr][q*8]);
        s8v b0 = *reinterpret_cast<const s8v*>(&Bs[wn*32 +  0 + lr][q*8]);
        s8v b1 = *reinterpret_cast<const s8v*>(&Bs[wn*32 + 16 + lr][q*8]);
        acc[0][0] = __builtin_amdgcn_mfma_f32_16x16x32_bf16(a0, b0, acc[0][0], 0,0,0);
        acc[0][1] = __builtin_amdgcn_mfma_f32_16x16x32_bf16(a0, b1, acc[0][1], 0,0,0);
        acc[1][0] = __builtin_amdgcn_mfma_f32_16x16x32_bf16(a1, b0, acc[1][0], 0,0,0);
        acc[1][1] = __builtin_amdgcn_mfma_f32_16x16x32_bf16(a1, b1, acc[1][1], 0,0,0);
        __syncthreads();
    }
    // D[row=q*4+i][col=lr]
    #pragma unroll
    for (int ms = 0; ms < 2; ++ms)
      #pragma unroll
      for (int ns = 0; ns < 2; ++ns) {
        int m = m0 + wm*32 + ms*16 + q*4;
        int n = n0 + wn*32 + ns*16 + lr;
        #pragma unroll
        for (int i = 0; i < 4; ++i)
            gi[(size_t)(m + i) * 3072 + n] = f2bf(acc[ms][ns][i]);
      }
}

// ---------------------------------------------------------------------------
// Cooperative GRU recurrence. 64 blocks x 128 threads (2 waves).
// Block owns 16 hidden cols j0..j0+15, computes r/z/n gates for them.
// Wave w = batch m-tile (rows 16w..16w+15). One grid.sync per step.
// h double-buffered: fp32 carry + bf16 shadow for MFMA A-operand.
// ---------------------------------------------------------------------------
__global__ __launch_bounds__(128) void k_gru(
        const float* __restrict__ pad,   // [512][32]
        const short* __restrict__ gi,    // [16384][3072] bf16 (no bias)
        const short* __restrict__ Whht,  // [3072][1024] bf16
        const float* __restrict__ b_ih,  // [3072]
        const float* __restrict__ b_hh,  // [3072]
        float* __restrict__ hf,          // [2][32][1024]
        short* __restrict__ hb,          // [2][32][1024] bf16
        float* __restrict__ out) {
    cg::grid_group grid = cg::this_grid();
    int bid = blockIdx.x;                // 0..63
    int j0  = bid * 16;
    int tid = threadIdx.x;               // 0..127
    int w   = tid >> 6;                  // m-tile (0/1)
    int l   = tid & 63, lr = l & 15, q = l >> 4;

    // zero h buffer 0 (ws is poisoned 0xAA every call)
    for (int e = tid; e < 512; e += 128) {
        int b = e >> 4, jj = e & 15;
        hf[b * 1024 + j0 + jj] = 0.0f;
        hb[b * 1024 + j0 + jj] = 0;
    }
    // per-lane constants: this lane's hidden column is j0+lr for all 3 gates
    int cr = j0 + lr, cz = 1024 + j0 + lr, cn = 2048 + j0 + lr;
    float bihr = b_ih[cr], bihz = b_ih[cz], bihn = b_ih[cn];
    float bhhr = b_hh[cr], bhhz = b_hh[cz], bhhn = b_hh[cn];
    const short* wr  = Whht + (size_t)cr * 1024 + q * 8;
    const short* wz  = Whht + (size_t)cz * 1024 + q * 8;
    const short* wnp = Whht + (size_t)cn * 1024 + q * 8;
    int arow = w * 16 + lr;              // A-operand batch row for this lane

    grid.sync();

    for (int t = 0; t < 512; ++t) {
        const short* hbr = hb + (t & 1) * 32768;
        const float* hfr = hf + (t & 1) * 32768;
        short* hbw = hb + ((t + 1) & 1) * 32768;
        float* hfw = hf + ((t + 1) & 1) * 32768;

        f4v ar = {0,0,0,0}, az = {0,0,0,0}, an = {0,0,0,0};
        const short* ha = hbr + arow * 1024 + q * 8;
        #pragma unroll 4
        for (int kc = 0; kc < 1024; kc += 32) {
            s8v a8 = *reinterpret_cast<const s8v*>(ha  + kc);
            s8v r8 = *reinterpret_cast<const s8v*>(wr  + kc);
            s8v z8 = *reinterpret_cast<const s8v*>(wz  + kc);
            s8v n8 = *reinterpret_cast<const s8v*>(wnp + kc);
            ar = __builtin_amdgcn_mfma_f32_16x16x32_bf16(a8, r8, ar, 0,0,0);
            az = __builtin_amdgcn_mfma_f32_16x16x32_bf16(a8, z8, az, 0,0,0);
            an = __builtin_amdgcn_mfma_f32_16x16x32_bf16(a8, n8, an, 0,0,0);
        }
        #pragma unroll
        for (int i = 0; i < 4; ++i) {
            int b = w * 16 + q * 4 + i;
            int j = j0 + lr;
            const short* gp = gi + (size_t)(t * 32 + b) * 3072;
            float gir = bf2f(gp[cr]) + bihr;
            float giz = bf2f(gp[cz]) + bihz;
            float gin = bf2f(gp[cn]) + bihn;
            float ghr = ar[i] + bhhr;
            float ghz = az[i] + bhhz;
            float ghn = an[i] + bhhn;
            float r = 1.0f / (1.0f + __expf(-(gir + ghr)));
            float z = 1.0f / (1.0f + __expf(-(giz + ghz)));
            float n = tanhf(gin + r * ghn);
            float hp = hfr[b * 1024 + j];
            float hnew = (1.0f - z) * n + z * hp;
            float p = pad[t * 32 + b];
            hnew = p * hp + (1.0f - p) * hnew;
            hfw[b * 1024 + j] = hnew;
            hbw[b * 1024 + j] = f2bf(hnew);
            out[(size_t)(t * 32 + b) * 1024 + j] = hnew;
            if (t == 511) {
                out[16777216 + b * 1024 + j] = hnew;   // outputs[-1]
                out[16809984 + b * 1024 + j] = hnew;   // h_last
            }
        }
        grid.sync();
    }
}

// ---------------------------------------------------------------------------
extern "C" void kernel_launch(void* const* d_in, const int* in_sizes, int n_in,
                              void* d_out, int out_size, void* d_ws, size_t ws_size,
                              hipStream_t stream) {
    const float* X   = (const float*)d_in[0];
    const float* pad = (const float*)d_in[1];
    const float* Wih = (const float*)d_in[2];
    const float* Whh = (const float*)d_in[3];
    const float* bih = (const float*)d_in[4];
    const float* bhh = (const float*)d_in[5];
    float* out = (float*)d_out;

    char* ws = (char*)d_ws;
    // ws layout (bytes):
    //   gi bf16   : 16384*3072*2 = 100663296
    //   Wih_t bf16:  3072*1024*2 =   6291456
    //   Whh_t bf16:  3072*1024*2 =   6291456
    //   h fp32 x2 :  2*32*1024*4 =    262144
    //   h bf16 x2 :  2*32*1024*2 =    131072   (total ~108.4 MB)
    short* gi    = (short*)(ws);
    short* Wih_t = (short*)(ws + 100663296);
    short* Whh_t = (short*)(ws + 106954752);
    float* hf    = (float*)(ws + 113246208);
    short* hb    = (short*)(ws + 113508352);

    hipLaunchKernelGGL(k_transpose_bf16, dim3(1536), dim3(256), 0, stream, Wih, Wih_t);
    hipLaunchKernelGGL(k_transpose_bf16, dim3(1536), dim3(256), 0, stream, Whh, Whh_t);
    hipLaunchKernelGGL(k_gemm_gi, dim3(256 * 48), dim3(256), 0, stream, X, Wih_t, gi);

    void* args[] = { (void*)&pad, (void*)&gi, (void*)&Whh_t, (void*)&bih,
                     (void*)&bhh, (void*)&hf, (void*)&hb, (void*)&out };
    hipLaunchCooperativeKernel((void*)k_gru, dim3(64), dim3(128), args, 0, stream);
}

// Round 2
// 5277.058 us; speedup vs baseline: 2.1820x; 2.1820x over previous
//
#include <hip/hip_runtime.h>
#include <hip/hip_cooperative_groups.h>
#include <cmath>

namespace cg = cooperative_groups;

// T=512, B=32, D=1024, H=1024, 3H=3072
// d_out: outputs (512*32*1024) ++ outputs[-1] (32*1024) ++ h_last (32*1024)  fp32

typedef short s8v  __attribute__((ext_vector_type(8)));   // 8 x bf16 (raw bits)
typedef float f4v  __attribute__((ext_vector_type(4)));   // MFMA accumulator

#define NB 64   // blocks in the cooperative GRU grid

__device__ __forceinline__ short f2bf(float f) {
    return __builtin_bit_cast(short, (__bf16)f);          // RNE convert
}
__device__ __forceinline__ float bf2f(short s) {
    return (float)__builtin_bit_cast(__bf16, s);
}

// ---------------------------------------------------------------------------
// Transpose W [1024][3072] fp32  ->  Wt [3072][1024] bf16 (so B-fragments are
// contiguous-in-k 16B loads). LDS tile 32(k) x 64(n).
// ---------------------------------------------------------------------------
__global__ __launch_bounds__(256) void k_transpose_bf16(
        const float* __restrict__ W, short* __restrict__ Wt) {
    __shared__ short Ls[32][72];                 // pad 64->72 vs bank conflicts
    int bk = blockIdx.x & 31;                    // 32 k-tiles
    int bn = blockIdx.x >> 5;                    // 48 n-tiles
    int k0 = bk * 32, n0 = bn * 64;
    int tid = threadIdx.x;
    {
        int r  = tid >> 3;                       // 0..31 (k)
        int c0 = (tid & 7) * 8;                  // 0..56 (n)
        const float* src = W + (size_t)(k0 + r) * 3072 + n0 + c0;
        float4 f0 = *reinterpret_cast<const float4*>(src);
        float4 f1 = *reinterpret_cast<const float4*>(src + 4);
        Ls[r][c0+0] = f2bf(f0.x); Ls[r][c0+1] = f2bf(f0.y);
        Ls[r][c0+2] = f2bf(f0.z); Ls[r][c0+3] = f2bf(f0.w);
        Ls[r][c0+4] = f2bf(f1.x); Ls[r][c0+5] = f2bf(f1.y);
        Ls[r][c0+6] = f2bf(f1.z); Ls[r][c0+7] = f2bf(f1.w);
    }
    __syncthreads();
    {
        int j   = tid >> 2;                      // 0..63 (n)
        int kk0 = (tid & 3) * 8;                 // 0..24 (k)
        s8v v;
        #pragma unroll
        for (int s = 0; s < 8; ++s) v[s] = Ls[kk0 + s][j];
        *reinterpret_cast<s8v*>(Wt + (size_t)(n0 + j) * 1024 + k0 + kk0) = v;
    }
}

// ---------------------------------------------------------------------------
// gi = X @ W_ih  (bias folded in later).  M=16384, N=3072, K=1024.
// 64x64 tile / block, 4 waves in 2x2, each wave 32x32 via 4x mfma 16x16x32.
// Output stored bf16.
// ---------------------------------------------------------------------------
__global__ __launch_bounds__(256) void k_gemm_gi(
        const float* __restrict__ X, const short* __restrict__ Wt,
        short* __restrict__ gi) {
    __shared__ short As[64][40];                 // 32 k + pad 8 (2-way only)
    __shared__ short Bs[64][40];
    int bm = blockIdx.x & 255;                   // 256 m-tiles
    int bn = blockIdx.x >> 8;                    // 48 n-tiles
    int m0 = bm * 64, n0 = bn * 64;
    int tid = threadIdx.x;
    int wid = tid >> 6, l = tid & 63;
    int wm = wid >> 1, wn = wid & 1;
    int lr = l & 15, q = l >> 4;
    f4v acc[2][2] = {};
    int sr = tid >> 2;                           // 0..63
    int sc = (tid & 3) * 8;                      // 0,8,16,24

    for (int kc = 0; kc < 1024; kc += 32) {
        const float* asrc = X + (size_t)(m0 + sr) * 1024 + kc + sc;
        float4 f0 = *reinterpret_cast<const float4*>(asrc);
        float4 f1 = *reinterpret_cast<const float4*>(asrc + 4);
        s8v av;
        av[0]=f2bf(f0.x); av[1]=f2bf(f0.y); av[2]=f2bf(f0.z); av[3]=f2bf(f0.w);
        av[4]=f2bf(f1.x); av[5]=f2bf(f1.y); av[6]=f2bf(f1.z); av[7]=f2bf(f1.w);
        *reinterpret_cast<s8v*>(&As[sr][sc]) = av;
        *reinterpret_cast<s8v*>(&Bs[sr][sc]) =
            *reinterpret_cast<const s8v*>(Wt + (size_t)(n0 + sr) * 1024 + kc + sc);
        __syncthreads();
        // A[m=lr][k=q*8+j], B[k=q*8+j][n=lr]
        s8v a0 = *reinterpret_cast<const s8v*>(&As[wm*32 +  0 + lr][q*8]);
        s8v a1 = *reinterpret_cast<const s8v*>(&As[wm*32 + 16 + lr][q*8]);
        s8v b0 = *reinterpret_cast<const s8v*>(&Bs[wn*32 +  0 + lr][q*8]);
        s8v b1 = *reinterpret_cast<const s8v*>(&Bs[wn*32 + 16 + lr][q*8]);
        acc[0][0] = __builtin_amdgcn_mfma_f32_16x16x32_bf16(a0, b0, acc[0][0], 0,0,0);
        acc[0][1] = __builtin_amdgcn_mfma_f32_16x16x32_bf16(a0, b1, acc[0][1], 0,0,0);
        acc[1][0] = __builtin_amdgcn_mfma_f32_16x16x32_bf16(a1, b0, acc[1][0], 0,0,0);
        acc[1][1] = __builtin_amdgcn_mfma_f32_16x16x32_bf16(a1, b1, acc[1][1], 0,0,0);
        __syncthreads();
    }
    // D[row=q*4+i][col=lr]
    #pragma unroll
    for (int ms = 0; ms < 2; ++ms)
      #pragma unroll
      for (int ns = 0; ns < 2; ++ns) {
        int m = m0 + wm*32 + ms*16 + q*4;
        int n = n0 + wn*32 + ns*16 + lr;
        #pragma unroll
        for (int i = 0; i < 4; ++i)
            gi[(size_t)(m + i) * 3072 + n] = f2bf(acc[ms][ns][i]);
      }
}

// ---------------------------------------------------------------------------
// Cooperative GRU recurrence. 64 blocks x 128 threads (2 waves).
// Block owns 16 hidden cols j0..j0+15; W_hh^T slice (3 gates x 16 cols x 1024)
// staged in LDS once (96.75 KB, stride-padded). One custom grid barrier/step
// (monotonic atomic counter + threadfence release/acquire). h carried as
// per-lane fp32 registers + global bf16 shadow (double-buffered) for MFMA.
// ---------------------------------------------------------------------------
__global__ __launch_bounds__(128) void k_gru(
        const float* __restrict__ pad,   // [512][32]
        const short* __restrict__ gi,    // [16384][3072] bf16 (no bias)
        const short* __restrict__ Whht,  // [3072][1024] bf16
        const float* __restrict__ b_ih,  // [3072]
        const float* __restrict__ b_hh,  // [3072]
        short* __restrict__ hb,          // [2][32][1024] bf16 (buf0 pre-zeroed)
        int*   __restrict__ bar,         // pre-zeroed barrier counter
        float* __restrict__ out) {
    extern __shared__ short wlds[];      // [3][16] rows, stride 1032 shorts
    const int WS = 1032;                 // 1024 + 8 pad: ds_read_b128 at floor
    int bid = blockIdx.x;                // 0..63
    int j0  = bid * 16;
    int tid = threadIdx.x;               // 0..127
    int w   = tid >> 6;                  // m-tile (0/1)
    int l   = tid & 63, lr = l & 15, q = l >> 4;

    // Stage the weight slice: 48 rows (gate g, col c) x 1024 shorts.
    for (int idx = tid; idx < 48 * 128; idx += 128) {
        int row = idx >> 7;              // 0..47
        int ko  = (idx & 127) * 8;       // 0..1016
        int g = row >> 4, c = row & 15;
        *reinterpret_cast<s8v*>(&wlds[(g * 16 + c) * WS + ko]) =
            *reinterpret_cast<const s8v*>(Whht + (size_t)(g * 1024 + j0 + c) * 1024 + ko);
    }
    __syncthreads();

    int cr = j0 + lr, cz = 1024 + j0 + lr, cn = 2048 + j0 + lr;
    float bihr = b_ih[cr], bihz = b_ih[cz], bihn = b_ih[cn];
    float bhhr = b_hh[cr], bhhz = b_hh[cz], bhhn = b_hh[cn];
    const short* w_r = &wlds[(0 * 16 + lr) * WS + q * 8];
    const short* w_z = &wlds[(1 * 16 + lr) * WS + q * 8];
    const short* w_n = &wlds[(2 * 16 + lr) * WS + q * 8];
    int arow = w * 16 + lr;              // A-operand batch row for this lane
    float hp[4] = {0.f, 0.f, 0.f, 0.f};  // lane-owned h_prev (b = w*16+q*4+i, j = j0+lr)

    for (int t = 0; t < 512; ++t) {
        const short* hbr = hb + (t & 1) * 32768;
        short* hbw = hb + ((t + 1) & 1) * 32768;

        // Hoisted gi/pad loads — independent of h, hide behind the MFMA chain.
        float gir[4], giz[4], gin[4], pv[4];
        #pragma unroll
        for (int i = 0; i < 4; ++i) {
            int b = w * 16 + q * 4 + i;
            const short* gp = gi + (size_t)(t * 32 + b) * 3072;
            gir[i] = bf2f(gp[cr]) + bihr;
            giz[i] = bf2f(gp[cz]) + bihz;
            gin[i] = bf2f(gp[cn]) + bihn;
            pv[i]  = pad[t * 32 + b];
        }

        f4v ar = {0,0,0,0}, az = {0,0,0,0}, an = {0,0,0,0};
        const short* ha = hbr + arow * 1024 + q * 8;
        #pragma unroll 8
        for (int kc = 0; kc < 1024; kc += 32) {
            s8v a8 = *reinterpret_cast<const s8v*>(ha + kc);
            s8v r8 = *reinterpret_cast<const s8v*>(w_r + kc);
            s8v z8 = *reinterpret_cast<const s8v*>(w_z + kc);
            s8v n8 = *reinterpret_cast<const s8v*>(w_n + kc);
            ar = __builtin_amdgcn_mfma_f32_16x16x32_bf16(a8, r8, ar, 0,0,0);
            az = __builtin_amdgcn_mfma_f32_16x16x32_bf16(a8, z8, az, 0,0,0);
            an = __builtin_amdgcn_mfma_f32_16x16x32_bf16(a8, n8, an, 0,0,0);
        }

        #pragma unroll
        for (int i = 0; i < 4; ++i) {
            int b = w * 16 + q * 4 + i;
            int j = j0 + lr;
            float r = 1.0f / (1.0f + __expf(-(gir[i] + ar[i] + bhhr)));
            float z = 1.0f / (1.0f + __expf(-(giz[i] + az[i] + bhhz)));
            float n = tanhf(gin[i] + r * (an[i] + bhhn));
            float hnew = (1.0f - z) * n + z * hp[i];
            hnew = pv[i] * hp[i] + (1.0f - pv[i]) * hnew;
            hp[i] = hnew;
            hbw[b * 1024 + j] = f2bf(hnew);
            out[(size_t)(t * 32 + b) * 1024 + j] = hnew;
            if (t == 511) {
                out[16777216 + b * 1024 + j] = hnew;   // outputs[-1]
                out[16809984 + b * 1024 + j] = hnew;   // h_last
            }
        }

        if (t < 511) {
            __syncthreads();                       // drains this block's stores to L2
            if (tid == 0) {
                __threadfence();                   // release: wb L2 -> device visible
                __hip_atomic_fetch_add(bar, 1, __ATOMIC_RELAXED, __HIP_MEMORY_SCOPE_AGENT);
                int target = (t + 1) * NB;
                while (__hip_atomic_load(bar, __ATOMIC_RELAXED, __HIP_MEMORY_SCOPE_AGENT) < target) { }
                __threadfence();                   // acquire: inv stale L1/L2
            }
            __syncthreads();
        }
    }
}

// ---------------------------------------------------------------------------
extern "C" void kernel_launch(void* const* d_in, const int* in_sizes, int n_in,
                              void* d_out, int out_size, void* d_ws, size_t ws_size,
                              hipStream_t stream) {
    const float* X   = (const float*)d_in[0];
    const float* pad = (const float*)d_in[1];
    const float* Wih = (const float*)d_in[2];
    const float* Whh = (const float*)d_in[3];
    const float* bih = (const float*)d_in[4];
    const float* bhh = (const float*)d_in[5];
    float* out = (float*)d_out;

    char* ws = (char*)d_ws;
    // ws layout (bytes):
    //   gi bf16   : 16384*3072*2 = 100663296
    //   Wih_t bf16:  3072*1024*2 =   6291456   @ 100663296
    //   Whh_t bf16:  3072*1024*2 =   6291456   @ 106954752
    //   hb bf16 x2:  2*32*1024*2 =    131072   @ 113246208
    //   bar       :  4                         @ 113377280
    short* gi    = (short*)(ws);
    short* Wih_t = (short*)(ws + 100663296);
    short* Whh_t = (short*)(ws + 106954752);
    short* hb    = (short*)(ws + 113246208);
    int*   bar   = (int*)  (ws + 113377280);

    // Zero h0 shadow (buffer 0) and the barrier counter (ws is 0xAA-poisoned).
    hipMemsetAsync(hb, 0, 65536, stream);
    hipMemsetAsync(bar, 0, 4, stream);

    hipLaunchKernelGGL(k_transpose_bf16, dim3(1536), dim3(256), 0, stream, Wih, Wih_t);
    hipLaunchKernelGGL(k_transpose_bf16, dim3(1536), dim3(256), 0, stream, Whh, Whh_t);
    hipLaunchKernelGGL(k_gemm_gi, dim3(256 * 48), dim3(256), 0, stream, X, Wih_t, gi);

    hipFuncSetAttribute((const void*)k_gru,
                        hipFuncAttributeMaxDynamicSharedMemorySize, 99072);
    void* args[] = { (void*)&pad, (void*)&gi, (void*)&Whh_t, (void*)&bih,
                     (void*)&bhh, (void*)&hb, (void*)&bar, (void*)&out };
    hipLaunchCooperativeKernel((void*)k_gru, dim3(NB), dim3(128), args, 99072, stream);
}

// Round 3
// 4636.556 us; speedup vs baseline: 2.4835x; 1.1381x over previous
//
#include <hip/hip_runtime.h>
#include <cmath>

// T=512, B=32, D=1024, H=1024, 3H=3072
// d_out: outputs (512*32*1024) ++ outputs[-1] (32*1024) ++ h_last (32*1024)  fp32

typedef short s8v  __attribute__((ext_vector_type(8)));   // 8 x bf16 (raw bits)
typedef float f4v  __attribute__((ext_vector_type(4)));   // MFMA accumulator

#define NB 64   // blocks in the cooperative GRU grid

__device__ __forceinline__ short f2bf(float f) {
    return __builtin_bit_cast(short, (__bf16)f);          // RNE convert
}
__device__ __forceinline__ float bf2f(short s) {
    return (float)__builtin_bit_cast(__bf16, s);
}

// ---------------------------------------------------------------------------
// Transpose W [1024][3072] fp32  ->  Wt [3072][1024] bf16.
// ---------------------------------------------------------------------------
__global__ __launch_bounds__(256) void k_transpose_bf16(
        const float* __restrict__ W, short* __restrict__ Wt) {
    __shared__ short Ls[32][72];
    int bk = blockIdx.x & 31;
    int bn = blockIdx.x >> 5;
    int k0 = bk * 32, n0 = bn * 64;
    int tid = threadIdx.x;
    {
        int r  = tid >> 3;
        int c0 = (tid & 7) * 8;
        const float* src = W + (size_t)(k0 + r) * 3072 + n0 + c0;
        float4 f0 = *reinterpret_cast<const float4*>(src);
        float4 f1 = *reinterpret_cast<const float4*>(src + 4);
        Ls[r][c0+0] = f2bf(f0.x); Ls[r][c0+1] = f2bf(f0.y);
        Ls[r][c0+2] = f2bf(f0.z); Ls[r][c0+3] = f2bf(f0.w);
        Ls[r][c0+4] = f2bf(f1.x); Ls[r][c0+5] = f2bf(f1.y);
        Ls[r][c0+6] = f2bf(f1.z); Ls[r][c0+7] = f2bf(f1.w);
    }
    __syncthreads();
    {
        int j   = tid >> 2;
        int kk0 = (tid & 3) * 8;
        s8v v;
        #pragma unroll
        for (int s = 0; s < 8; ++s) v[s] = Ls[kk0 + s][j];
        *reinterpret_cast<s8v*>(Wt + (size_t)(n0 + j) * 1024 + k0 + kk0) = v;
    }
}

// ---------------------------------------------------------------------------
// gi = X @ W_ih.  M=16384, N=3072, K=1024.  Output bf16.
// ---------------------------------------------------------------------------
__global__ __launch_bounds__(256) void k_gemm_gi(
        const float* __restrict__ X, const short* __restrict__ Wt,
        short* __restrict__ gi) {
    __shared__ short As[64][40];
    __shared__ short Bs[64][40];
    int bm = blockIdx.x & 255;
    int bn = blockIdx.x >> 8;
    int m0 = bm * 64, n0 = bn * 64;
    int tid = threadIdx.x;
    int wid = tid >> 6, l = tid & 63;
    int wm = wid >> 1, wn = wid & 1;
    int lr = l & 15, q = l >> 4;
    f4v acc[2][2] = {};
    int sr = tid >> 2;
    int sc = (tid & 3) * 8;

    for (int kc = 0; kc < 1024; kc += 32) {
        const float* asrc = X + (size_t)(m0 + sr) * 1024 + kc + sc;
        float4 f0 = *reinterpret_cast<const float4*>(asrc);
        float4 f1 = *reinterpret_cast<const float4*>(asrc + 4);
        s8v av;
        av[0]=f2bf(f0.x); av[1]=f2bf(f0.y); av[2]=f2bf(f0.z); av[3]=f2bf(f0.w);
        av[4]=f2bf(f1.x); av[5]=f2bf(f1.y); av[6]=f2bf(f1.z); av[7]=f2bf(f1.w);
        *reinterpret_cast<s8v*>(&As[sr][sc]) = av;
        *reinterpret_cast<s8v*>(&Bs[sr][sc]) =
            *reinterpret_cast<const s8v*>(Wt + (size_t)(n0 + sr) * 1024 + kc + sc);
        __syncthreads();
        s8v a0 = *reinterpret_cast<const s8v*>(&As[wm*32 +  0 + lr][q*8]);
        s8v a1 = *reinterpret_cast<const s8v*>(&As[wm*32 + 16 + lr][q*8]);
        s8v b0 = *reinterpret_cast<const s8v*>(&Bs[wn*32 +  0 + lr][q*8]);
        s8v b1 = *reinterpret_cast<const s8v*>(&Bs[wn*32 + 16 + lr][q*8]);
        acc[0][0] = __builtin_amdgcn_mfma_f32_16x16x32_bf16(a0, b0, acc[0][0], 0,0,0);
        acc[0][1] = __builtin_amdgcn_mfma_f32_16x16x32_bf16(a0, b1, acc[0][1], 0,0,0);
        acc[1][0] = __builtin_amdgcn_mfma_f32_16x16x32_bf16(a1, b0, acc[1][0], 0,0,0);
        acc[1][1] = __builtin_amdgcn_mfma_f32_16x16x32_bf16(a1, b1, acc[1][1], 0,0,0);
        __syncthreads();
    }
    #pragma unroll
    for (int ms = 0; ms < 2; ++ms)
      #pragma unroll
      for (int ns = 0; ns < 2; ++ns) {
        int m = m0 + wm*32 + ms*16 + q*4;
        int n = n0 + wn*32 + ns*16 + lr;
        #pragma unroll
        for (int i = 0; i < 4; ++i)
            gi[(size_t)(m + i) * 3072 + n] = f2bf(acc[ms][ns][i]);
      }
}

// ---------------------------------------------------------------------------
// Cooperative GRU recurrence v3. 64 blocks x 128 threads.
// MFMA roles: A = W_hh^T slice (LDS), B = h (coherent LLC loads) ->
// D[row=j-offset][col=batch] so each lane owns (batch b, 4 consecutive j).
// h exchange via agent-scope write-through atomics (sc0sc1) — NO cache-wide
// fences anywhere; L2 stays warm for the gi stream. One relaxed-atomic
// counter barrier per step.
// ---------------------------------------------------------------------------
__global__ __launch_bounds__(128) void k_gru(
        const float* __restrict__ pad,   // [512][32]
        const short* __restrict__ gi,    // [16384][3072] bf16 (no bias)
        const short* __restrict__ Whht,  // [3072][1024] bf16
        const float* __restrict__ b_ih,  // [3072]
        const float* __restrict__ b_hh,  // [3072]
        short* __restrict__ hb,          // [2][32][1024] bf16 (buf0 pre-zeroed)
        int*   __restrict__ bar,         // pre-zeroed barrier counter
        float* __restrict__ out) {
    extern __shared__ short wlds[];      // 48 rows x 1024, stride 1032 shorts
    const int WS = 1032;
    int bid = blockIdx.x;                // 0..63
    int j0  = bid * 16;
    int tid = threadIdx.x;               // 0..127
    int w   = tid >> 6;                  // batch half (n-tile)
    int l   = tid & 63, lr = l & 15, q = l >> 4;

    // Stage weight slice: rows (gate g, col c) x 1024 shorts.
    for (int idx = tid; idx < 48 * 128; idx += 128) {
        int row = idx >> 7;
        int ko  = (idx & 127) * 8;
        int g = row >> 4, c = row & 15;
        *reinterpret_cast<s8v*>(&wlds[(g * 16 + c) * WS + ko]) =
            *reinterpret_cast<const s8v*>(Whht + (size_t)(g * 1024 + j0 + c) * 1024 + ko);
    }
    __syncthreads();

    int jq = j0 + q * 4;                 // first of this lane's 4 j-cols
    int b  = w * 16 + lr;                // this lane's batch row
    // bias sums (b_ih + b_hh), per owned j-col
    f4v sbr = *reinterpret_cast<const f4v*>(b_ih + jq)
            + *reinterpret_cast<const f4v*>(b_hh + jq);
    f4v sbz = *reinterpret_cast<const f4v*>(b_ih + 1024 + jq)
            + *reinterpret_cast<const f4v*>(b_hh + 1024 + jq);
    f4v sbn_i = *reinterpret_cast<const f4v*>(b_ih + 2048 + jq);   // gi-side n bias
    f4v sbn_h = *reinterpret_cast<const f4v*>(b_hh + 2048 + jq);   // gh-side n bias
    const short* w_r = &wlds[(0 * 16 + lr) * WS + q * 8];
    const short* w_z = &wlds[(1 * 16 + lr) * WS + q * 8];
    const short* w_n = &wlds[(2 * 16 + lr) * WS + q * 8];
    float hp[4] = {0.f, 0.f, 0.f, 0.f};  // register-carried h_prev (b, jq+i)

    for (int t = 0; t < 512; ++t) {
        int rowg = t * 32 + b;
        // gi + pad loads (vector, independent of h)
        const short* gp = gi + (size_t)rowg * 3072 + jq;
        union { unsigned long long u; short s[4]; } gr_, gz_, gn_;
        gr_.u = *reinterpret_cast<const unsigned long long*>(gp);
        gz_.u = *reinterpret_cast<const unsigned long long*>(gp + 1024);
        gn_.u = *reinterpret_cast<const unsigned long long*>(gp + 2048);
        float pv = pad[rowg];

        // B-operand base: h[b][k], read as coherent 8B atomics from LLC
        unsigned long long* hbr = (unsigned long long*)(hb + (t & 1) * 32768)
                                  + (size_t)b * 256 + q * 2;
        f4v ar = {0,0,0,0}, az = {0,0,0,0}, an = {0,0,0,0};
        #pragma unroll
        for (int it = 0; it < 32; ++it) {
            union { unsigned long long u[2]; s8v v; } hx;
            hx.u[0] = __hip_atomic_load(hbr + it * 8,     __ATOMIC_RELAXED, __HIP_MEMORY_SCOPE_AGENT);
            hx.u[1] = __hip_atomic_load(hbr + it * 8 + 1, __ATOMIC_RELAXED, __HIP_MEMORY_SCOPE_AGENT);
            s8v r8 = *reinterpret_cast<const s8v*>(w_r + it * 32);
            s8v z8 = *reinterpret_cast<const s8v*>(w_z + it * 32);
            s8v n8 = *reinterpret_cast<const s8v*>(w_n + it * 32);
            ar = __builtin_amdgcn_mfma_f32_16x16x32_bf16(r8, hx.v, ar, 0,0,0);
            az = __builtin_amdgcn_mfma_f32_16x16x32_bf16(z8, hx.v, az, 0,0,0);
            an = __builtin_amdgcn_mfma_f32_16x16x32_bf16(n8, hx.v, an, 0,0,0);
        }

        #pragma unroll
        for (int i = 0; i < 4; ++i) {
            float xr = bf2f(gr_.s[i]) + ar[i] + sbr[i];
            float xz = bf2f(gz_.s[i]) + az[i] + sbz[i];
            float r  = __builtin_amdgcn_rcpf(1.f + __expf(-xr));
            float z  = __builtin_amdgcn_rcpf(1.f + __expf(-xz));
            float xn = bf2f(gn_.s[i]) + sbn_i[i] + r * (an[i] + sbn_h[i]);
            float e2 = __expf(2.f * xn);
            float n  = 1.f - 2.f * __builtin_amdgcn_rcpf(1.f + e2);   // tanh, inf-safe
            float hnv = (1.f - z) * n + z * hp[i];
            hnv = pv * hp[i] + (1.f - pv) * hnv;
            hp[i] = hnv;
        }

        // h shadow store: 4 bf16 packed -> one 8B write-through atomic
        union { unsigned long long u; short s[4]; } pk;
        pk.s[0] = f2bf(hp[0]); pk.s[1] = f2bf(hp[1]);
        pk.s[2] = f2bf(hp[2]); pk.s[3] = f2bf(hp[3]);
        unsigned long long* hbw = (unsigned long long*)(hb + ((t + 1) & 1) * 32768)
                                  + (size_t)b * 256 + (jq >> 2);
        __hip_atomic_store(hbw, pk.u, __ATOMIC_RELAXED, __HIP_MEMORY_SCOPE_AGENT);

        float4 o4 = { hp[0], hp[1], hp[2], hp[3] };
        *reinterpret_cast<float4*>(out + (size_t)rowg * 1024 + jq) = o4;
        if (t == 511) {
            *reinterpret_cast<float4*>(out + 16777216 + b * 1024 + jq) = o4;
            *reinterpret_cast<float4*>(out + 16809984 + b * 1024 + jq) = o4;
        }

        if (t < 511) {
            __builtin_amdgcn_s_waitcnt(0);     // insurance: drain vmem (h store at LLC)
            __syncthreads();                   // all waves' stores drained pre-barrier
            if (tid == 0) {
                __hip_atomic_fetch_add(bar, 1, __ATOMIC_RELAXED, __HIP_MEMORY_SCOPE_AGENT);
                int target = (t + 1) * NB;
                while (__hip_atomic_load(bar, __ATOMIC_RELAXED, __HIP_MEMORY_SCOPE_AGENT) < target) { }
            }
            __syncthreads();
        }
    }
}

// ---------------------------------------------------------------------------
extern "C" void kernel_launch(void* const* d_in, const int* in_sizes, int n_in,
                              void* d_out, int out_size, void* d_ws, size_t ws_size,
                              hipStream_t stream) {
    const float* X   = (const float*)d_in[0];
    const float* pad = (const float*)d_in[1];
    const float* Wih = (const float*)d_in[2];
    const float* Whh = (const float*)d_in[3];
    const float* bih = (const float*)d_in[4];
    const float* bhh = (const float*)d_in[5];
    float* out = (float*)d_out;

    char* ws = (char*)d_ws;
    short* gi    = (short*)(ws);
    short* Wih_t = (short*)(ws + 100663296);
    short* Whh_t = (short*)(ws + 106954752);
    short* hb    = (short*)(ws + 113246208);
    int*   bar   = (int*)  (ws + 113377280);

    // Zero h0 shadow (buffer 0) and the barrier counter (ws is 0xAA-poisoned).
    hipMemsetAsync(hb, 0, 65536, stream);
    hipMemsetAsync(bar, 0, 4, stream);

    hipLaunchKernelGGL(k_transpose_bf16, dim3(1536), dim3(256), 0, stream, Wih, Wih_t);
    hipLaunchKernelGGL(k_transpose_bf16, dim3(1536), dim3(256), 0, stream, Whh, Whh_t);
    hipLaunchKernelGGL(k_gemm_gi, dim3(256 * 48), dim3(256), 0, stream, X, Wih_t, gi);

    hipFuncSetAttribute((const void*)k_gru,
                        hipFuncAttributeMaxDynamicSharedMemorySize, 99072);
    void* args[] = { (void*)&pad, (void*)&gi, (void*)&Whh_t, (void*)&bih,
                     (void*)&bhh, (void*)&hb, (void*)&bar, (void*)&out };
    hipLaunchCooperativeKernel((void*)k_gru, dim3(NB), dim3(128), args, 99072, stream);
}

// Round 4
// 4029.491 us; speedup vs baseline: 2.8576x; 1.1507x over previous
//
#include <hip/hip_runtime.h>
#include <cmath>

// T=512, B=32, D=1024, H=1024, 3H=3072
// d_out: outputs (512*32*1024) ++ outputs[-1] (32*1024) ++ h_last (32*1024)  fp32

typedef short s8v  __attribute__((ext_vector_type(8)));   // 8 x bf16 (raw bits)
typedef float f4v  __attribute__((ext_vector_type(4)));   // MFMA accumulator

#define NB 64   // blocks in the GRU grid

__device__ __forceinline__ short f2bf(float f) {
    return __builtin_bit_cast(short, (__bf16)f);          // RNE convert
}
__device__ __forceinline__ float bf2f(short s) {
    return (float)__builtin_bit_cast(__bf16, s);
}

// ---------------------------------------------------------------------------
// Transpose W [1024][3072] fp32  ->  Wt [3072][1024] bf16.
// ---------------------------------------------------------------------------
__global__ __launch_bounds__(256) void k_transpose_bf16(
        const float* __restrict__ W, short* __restrict__ Wt) {
    __shared__ short Ls[32][72];
    int bk = blockIdx.x & 31;
    int bn = blockIdx.x >> 5;
    int k0 = bk * 32, n0 = bn * 64;
    int tid = threadIdx.x;
    {
        int r  = tid >> 3;
        int c0 = (tid & 7) * 8;
        const float* src = W + (size_t)(k0 + r) * 3072 + n0 + c0;
        float4 f0 = *reinterpret_cast<const float4*>(src);
        float4 f1 = *reinterpret_cast<const float4*>(src + 4);
        Ls[r][c0+0] = f2bf(f0.x); Ls[r][c0+1] = f2bf(f0.y);
        Ls[r][c0+2] = f2bf(f0.z); Ls[r][c0+3] = f2bf(f0.w);
        Ls[r][c0+4] = f2bf(f1.x); Ls[r][c0+5] = f2bf(f1.y);
        Ls[r][c0+6] = f2bf(f1.z); Ls[r][c0+7] = f2bf(f1.w);
    }
    __syncthreads();
    {
        int j   = tid >> 2;
        int kk0 = (tid & 3) * 8;
        s8v v;
        #pragma unroll
        for (int s = 0; s < 8; ++s) v[s] = Ls[kk0 + s][j];
        *reinterpret_cast<s8v*>(Wt + (size_t)(n0 + j) * 1024 + k0 + kk0) = v;
    }
}

// ---------------------------------------------------------------------------
// gi = X @ W_ih.  M=16384, N=3072, K=1024.  Output bf16.
// ---------------------------------------------------------------------------
__global__ __launch_bounds__(256) void k_gemm_gi(
        const float* __restrict__ X, const short* __restrict__ Wt,
        short* __restrict__ gi) {
    __shared__ short As[64][40];
    __shared__ short Bs[64][40];
    int bm = blockIdx.x & 255;
    int bn = blockIdx.x >> 8;
    int m0 = bm * 64, n0 = bn * 64;
    int tid = threadIdx.x;
    int wid = tid >> 6, l = tid & 63;
    int wm = wid >> 1, wn = wid & 1;
    int lr = l & 15, q = l >> 4;
    f4v acc[2][2] = {};
    int sr = tid >> 2;
    int sc = (tid & 3) * 8;

    for (int kc = 0; kc < 1024; kc += 32) {
        const float* asrc = X + (size_t)(m0 + sr) * 1024 + kc + sc;
        float4 f0 = *reinterpret_cast<const float4*>(asrc);
        float4 f1 = *reinterpret_cast<const float4*>(asrc + 4);
        s8v av;
        av[0]=f2bf(f0.x); av[1]=f2bf(f0.y); av[2]=f2bf(f0.z); av[3]=f2bf(f0.w);
        av[4]=f2bf(f1.x); av[5]=f2bf(f1.y); av[6]=f2bf(f1.z); av[7]=f2bf(f1.w);
        *reinterpret_cast<s8v*>(&As[sr][sc]) = av;
        *reinterpret_cast<s8v*>(&Bs[sr][sc]) =
            *reinterpret_cast<const s8v*>(Wt + (size_t)(n0 + sr) * 1024 + kc + sc);
        __syncthreads();
        s8v a0 = *reinterpret_cast<const s8v*>(&As[wm*32 +  0 + lr][q*8]);
        s8v a1 = *reinterpret_cast<const s8v*>(&As[wm*32 + 16 + lr][q*8]);
        s8v b0 = *reinterpret_cast<const s8v*>(&Bs[wn*32 +  0 + lr][q*8]);
        s8v b1 = *reinterpret_cast<const s8v*>(&Bs[wn*32 + 16 + lr][q*8]);
        acc[0][0] = __builtin_amdgcn_mfma_f32_16x16x32_bf16(a0, b0, acc[0][0], 0,0,0);
        acc[0][1] = __builtin_amdgcn_mfma_f32_16x16x32_bf16(a0, b1, acc[0][1], 0,0,0);
        acc[1][0] = __builtin_amdgcn_mfma_f32_16x16x32_bf16(a1, b0, acc[1][0], 0,0,0);
        acc[1][1] = __builtin_amdgcn_mfma_f32_16x16x32_bf16(a1, b1, acc[1][1], 0,0,0);
        __syncthreads();
    }
    #pragma unroll
    for (int ms = 0; ms < 2; ++ms)
      #pragma unroll
      for (int ns = 0; ns < 2; ++ns) {
        int m = m0 + wm*32 + ms*16 + q*4;
        int n = n0 + wn*32 + ns*16 + lr;
        #pragma unroll
        for (int i = 0; i < 4; ++i)
            gi[(size_t)(m + i) * 3072 + n] = f2bf(acc[ms][ns][i]);
      }
}

// ---------------------------------------------------------------------------
// GRU recurrence v4. 64 blocks x 128 threads (2 waves, each independent).
// Distributed flag sync: 128 per-WAVE flags (monotonic step counters).
//   produce: h-chunk atomic stores -> s_waitcnt(0) -> own flag := t+1
//   consume: all 64 lanes poll flags (u64/lane covers both waves of a block),
//            __all() across the wave, s_sleep backoff. No __syncthreads, no
//            central counter, no cache-wide fences. gi/pad prefetched one
//            step ahead; out stores after the flag store (drain in the spin).
// h loads issued as one burst of 64 u64 atomics into registers (1 block/CU,
// VGPRs free), then 32 MFMA iterations consume them in order.
// ---------------------------------------------------------------------------
__global__ __launch_bounds__(128, 1) void k_gru(
        const float* __restrict__ pad,   // [512][32]
        const short* __restrict__ gi,    // [16384][3072] bf16 (no bias)
        const short* __restrict__ Whht,  // [3072][1024] bf16
        const float* __restrict__ b_ih,  // [3072]
        const float* __restrict__ b_hh,  // [3072]
        short* __restrict__ hb,          // [2][32][1024] bf16 (buf0 pre-zeroed)
        unsigned* __restrict__ flags,    // [128] pre-zeroed per-wave step flags
        float* __restrict__ out) {
    extern __shared__ short wlds[];      // 48 rows x 1024, stride 1032 shorts
    const int WS = 1032;
    int bid = blockIdx.x;                // 0..63
    int j0  = bid * 16;
    int tid = threadIdx.x;               // 0..127
    int w   = tid >> 6;                  // batch half
    int l   = tid & 63, lr = l & 15, q = l >> 4;

    // Stage weight slice: rows (gate g, col c) x 1024 shorts. (both waves)
    for (int idx = tid; idx < 48 * 128; idx += 128) {
        int row = idx >> 7;
        int ko  = (idx & 127) * 8;
        int g = row >> 4, c = row & 15;
        *reinterpret_cast<s8v*>(&wlds[(g * 16 + c) * WS + ko]) =
            *reinterpret_cast<const s8v*>(Whht + (size_t)(g * 1024 + j0 + c) * 1024 + ko);
    }
    __syncthreads();                     // weights ready; last sync in kernel

    int jq = j0 + q * 4;                 // first of this lane's 4 j-cols
    int b  = w * 16 + lr;                // this lane's batch row
    f4v sbr = *reinterpret_cast<const f4v*>(b_ih + jq)
            + *reinterpret_cast<const f4v*>(b_hh + jq);
    f4v sbz = *reinterpret_cast<const f4v*>(b_ih + 1024 + jq)
            + *reinterpret_cast<const f4v*>(b_hh + 1024 + jq);
    f4v sbn_i = *reinterpret_cast<const f4v*>(b_ih + 2048 + jq);
    f4v sbn_h = *reinterpret_cast<const f4v*>(b_hh + 2048 + jq);
    const short* w_r = &wlds[(0 * 16 + lr) * WS + q * 8];
    const short* w_z = &wlds[(1 * 16 + lr) * WS + q * 8];
    const short* w_n = &wlds[(2 * 16 + lr) * WS + q * 8];
    float hp[4] = {0.f, 0.f, 0.f, 0.f};

    const unsigned long long* flags2 = (const unsigned long long*)flags;

    union u64s { unsigned long long u; short s[4]; };
    u64s gr_, gz_, gn_; float pv;
    {   // prefetch gi/pad for t=0
        const short* gp = gi + (size_t)b * 3072 + jq;
        gr_.u = *reinterpret_cast<const unsigned long long*>(gp);
        gz_.u = *reinterpret_cast<const unsigned long long*>(gp + 1024);
        gn_.u = *reinterpret_cast<const unsigned long long*>(gp + 2048);
        pv = pad[b];
    }

    for (int t = 0; t < 512; ++t) {
        if (t) {    // wait until every wave has published h_t
            unsigned uT = (unsigned)t;
            for (;;) {
                unsigned long long f = __hip_atomic_load(flags2 + l,
                        __ATOMIC_RELAXED, __HIP_MEMORY_SCOPE_AGENT);
                bool ok = ((unsigned)f >= uT) && ((unsigned)(f >> 32) >= uT);
                if (__all(ok)) break;
                __builtin_amdgcn_s_sleep(1);
            }
        }

        // Burst-issue all h loads (in-order completion matches MFMA order).
        const unsigned long long* hbr =
            (const unsigned long long*)(hb + (t & 1) * 32768) + (size_t)b * 256 + q * 2;
        unsigned long long hreg[64];
        #pragma unroll
        for (int it = 0; it < 32; ++it) {
            hreg[2*it]   = __hip_atomic_load(hbr + it * 8,
                               __ATOMIC_RELAXED, __HIP_MEMORY_SCOPE_AGENT);
            hreg[2*it+1] = __hip_atomic_load(hbr + it * 8 + 1,
                               __ATOMIC_RELAXED, __HIP_MEMORY_SCOPE_AGENT);
        }

        // Prefetch gi/pad for t+1 (independent; overlaps h latency + MFMA).
        u64s ngr, ngz, ngn; float npv;
        {
            int tn = (t < 511) ? (t + 1) : 511;
            const short* gp = gi + (size_t)(tn * 32 + b) * 3072 + jq;
            ngr.u = *reinterpret_cast<const unsigned long long*>(gp);
            ngz.u = *reinterpret_cast<const unsigned long long*>(gp + 1024);
            ngn.u = *reinterpret_cast<const unsigned long long*>(gp + 2048);
            npv = pad[tn * 32 + b];
        }

        f4v ar = {0,0,0,0}, az = {0,0,0,0}, an = {0,0,0,0};
        #pragma unroll
        for (int it = 0; it < 32; ++it) {
            union { unsigned long long u[2]; s8v v; } hx;
            hx.u[0] = hreg[2*it]; hx.u[1] = hreg[2*it+1];
            s8v r8 = *reinterpret_cast<const s8v*>(w_r + it * 32);
            s8v z8 = *reinterpret_cast<const s8v*>(w_z + it * 32);
            s8v n8 = *reinterpret_cast<const s8v*>(w_n + it * 32);
            ar = __builtin_amdgcn_mfma_f32_16x16x32_bf16(r8, hx.v, ar, 0,0,0);
            az = __builtin_amdgcn_mfma_f32_16x16x32_bf16(z8, hx.v, az, 0,0,0);
            an = __builtin_amdgcn_mfma_f32_16x16x32_bf16(n8, hx.v, an, 0,0,0);
        }

        #pragma unroll
        for (int i = 0; i < 4; ++i) {
            float xr = bf2f(gr_.s[i]) + ar[i] + sbr[i];
            float xz = bf2f(gz_.s[i]) + az[i] + sbz[i];
            float r  = __builtin_amdgcn_rcpf(1.f + __expf(-xr));
            float z  = __builtin_amdgcn_rcpf(1.f + __expf(-xz));
            float xn = bf2f(gn_.s[i]) + sbn_i[i] + r * (an[i] + sbn_h[i]);
            float e2 = __expf(2.f * xn);
            float n  = 1.f - 2.f * __builtin_amdgcn_rcpf(1.f + e2);   // tanh
            float hnv = (1.f - z) * n + z * hp[i];
            hnv = pv * hp[i] + (1.f - pv) * hnv;
            hp[i] = hnv;
        }

        int rowg = t * 32 + b;
        if (t < 511) {
            // publish h chunk, drain it, raise this wave's flag
            union { unsigned long long u; short s[4]; } pk;
            pk.s[0] = f2bf(hp[0]); pk.s[1] = f2bf(hp[1]);
            pk.s[2] = f2bf(hp[2]); pk.s[3] = f2bf(hp[3]);
            unsigned long long* hbw =
                (unsigned long long*)(hb + ((t + 1) & 1) * 32768)
                + (size_t)b * 256 + (jq >> 2);
            __hip_atomic_store(hbw, pk.u, __ATOMIC_RELAXED, __HIP_MEMORY_SCOPE_AGENT);
            __builtin_amdgcn_s_waitcnt(0);       // h store (and prefetch loads) done
            if (l == 0)
                __hip_atomic_store(flags + bid * 2 + w, (unsigned)(t + 1),
                                   __ATOMIC_RELAXED, __HIP_MEMORY_SCOPE_AGENT);
        }

        // out stores AFTER signaling — their drain overlaps the next spin
        float4 o4 = { hp[0], hp[1], hp[2], hp[3] };
        *reinterpret_cast<float4*>(out + (size_t)rowg * 1024 + jq) = o4;
        if (t == 511) {
            *reinterpret_cast<float4*>(out + 16777216 + b * 1024 + jq) = o4;
            *reinterpret_cast<float4*>(out + 16809984 + b * 1024 + jq) = o4;
        }

        gr_ = ngr; gz_ = ngz; gn_ = ngn; pv = npv;
    }
}

// ---------------------------------------------------------------------------
extern "C" void kernel_launch(void* const* d_in, const int* in_sizes, int n_in,
                              void* d_out, int out_size, void* d_ws, size_t ws_size,
                              hipStream_t stream) {
    const float* X   = (const float*)d_in[0];
    const float* pad = (const float*)d_in[1];
    const float* Wih = (const float*)d_in[2];
    const float* Whh = (const float*)d_in[3];
    const float* bih = (const float*)d_in[4];
    const float* bhh = (const float*)d_in[5];
    float* out = (float*)d_out;

    char* ws = (char*)d_ws;
    short*    gi    = (short*)(ws);
    short*    Wih_t = (short*)(ws + 100663296);
    short*    Whh_t = (short*)(ws + 106954752);
    short*    hb    = (short*)(ws + 113246208);
    unsigned* flags = (unsigned*)(ws + 113377280);

    // Zero h0 shadow (buffer 0) and the flag array (ws is 0xAA-poisoned).
    hipMemsetAsync(hb, 0, 65536, stream);
    hipMemsetAsync(flags, 0, 512, stream);

    hipLaunchKernelGGL(k_transpose_bf16, dim3(1536), dim3(256), 0, stream, Wih, Wih_t);
    hipLaunchKernelGGL(k_transpose_bf16, dim3(1536), dim3(256), 0, stream, Whh, Whh_t);
    hipLaunchKernelGGL(k_gemm_gi, dim3(256 * 48), dim3(256), 0, stream, X, Wih_t, gi);

    hipFuncSetAttribute((const void*)k_gru,
                        hipFuncAttributeMaxDynamicSharedMemorySize, 99072);
    hipLaunchKernelGGL(k_gru, dim3(NB), dim3(128), 99072, stream,
                       pad, gi, Whh_t, bih, bhh, hb, flags, out);
}